// Round 1
// baseline (445.386 us; speedup 1.0000x reference)
//
#include <hip/hip_runtime.h>
#include <hip/hip_bf16.h>
#include <math.h>

#define N_TOK 16384
#define D_DIM 1024
#define E_NUM 8
#define H_DIM 256
#define LN_EPS 1e-5f

#define BM 128
#define BN 128
#define BK 32
#define MAXTILES (N_TOK / BM + E_NUM)   /* 136 */
#define MP (MAXTILES * BM)              /* 17408 */

typedef __attribute__((ext_vector_type(8))) short bf16x8;
typedef __attribute__((ext_vector_type(4))) float f32x4;

__device__ __forceinline__ unsigned short f2bf(float f) {
  union { float f; unsigned u; } cv; cv.f = f;
  unsigned u = cv.u;
  u += 0x7fffu + ((u >> 16) & 1u);   // round-to-nearest-even
  return (unsigned short)(u >> 16);
}

__device__ __forceinline__ void gl_lds16(const void* g, void* l) {
  __builtin_amdgcn_global_load_lds(
      (const __attribute__((address_space(1))) unsigned int*)g,
      (__attribute__((address_space(3))) unsigned int*)l, 16, 0, 0);
}

// ---------------- gate + layernorm: one wave per token ----------------
__global__ __launch_bounds__(256) void smoe_gate(
    const float* __restrict__ x, const float* __restrict__ wg,
    const float* __restrict__ ln_s, const float* __restrict__ ln_b,
    unsigned short* __restrict__ xhat, int* __restrict__ eid,
    int* __restrict__ counts)
{
  int wave = threadIdx.x >> 6;
  int lane = threadIdx.x & 63;
  int t = blockIdx.x * 4 + wave;          // 4096 blocks * 4 waves = 16384
  const float4* xr  = (const float4*)(x + (size_t)t * D_DIM);
  const float4* wg4 = (const float4*)wg;
  float4 v[4];
  double lg[E_NUM] = {};
  double s = 0.0, ss = 0.0;
#pragma unroll
  for (int j = 0; j < 4; j++) {
    v[j] = xr[lane + 64 * j];
    s  += (double)v[j].x + (double)v[j].y + (double)v[j].z + (double)v[j].w;
    ss += (double)v[j].x * v[j].x + (double)v[j].y * v[j].y
        + (double)v[j].z * v[j].z + (double)v[j].w * v[j].w;
#pragma unroll
    for (int e = 0; e < E_NUM; e++) {
      float4 w = wg4[e * 256 + lane + 64 * j];
      lg[e] += (double)v[j].x * w.x + (double)v[j].y * w.y
             + (double)v[j].z * w.z + (double)v[j].w * w.w;
    }
  }
#pragma unroll
  for (int m = 1; m < 64; m <<= 1) {
#pragma unroll
    for (int e = 0; e < E_NUM; e++) lg[e] += __shfl_xor(lg[e], m, 64);
    s  += __shfl_xor(s, m, 64);
    ss += __shfl_xor(ss, m, 64);
  }
  int best = 0;
#pragma unroll
  for (int e = 1; e < E_NUM; e++) if (lg[e] > lg[best]) best = e;  // first-max tiebreak
  double mu = s / D_DIM;
  float mean = (float)mu;
  float var  = (float)(ss / D_DIM - mu * mu);
  float rstd = 1.0f / sqrtf(var + LN_EPS);
  if (lane == 0) {
    eid[t] = best;
    atomicAdd(&counts[best], 1);
  }
  const float4* s4 = (const float4*)(ln_s + (size_t)best * D_DIM);
  const float4* b4 = (const float4*)(ln_b + (size_t)best * D_DIM);
  ushort4* xo = (ushort4*)(xhat + (size_t)t * D_DIM);
#pragma unroll
  for (int j = 0; j < 4; j++) {
    float4 sc = s4[lane + 64 * j], bi = b4[lane + 64 * j];
    ushort4 o;
    o.x = f2bf((v[j].x - mean) * rstd * sc.x + bi.x);
    o.y = f2bf((v[j].y - mean) * rstd * sc.y + bi.y);
    o.z = f2bf((v[j].z - mean) * rstd * sc.z + bi.z);
    o.w = f2bf((v[j].w - mean) * rstd * sc.w + bi.w);
    xo[lane + 64 * j] = o;
  }
}

// ---------------- scan: padded segment bases + tile->expert map ----------------
__global__ void smoe_scan(const int* __restrict__ counts, int* __restrict__ base,
                          int* __restrict__ texp, int* __restrict__ tokp)
{
  int tid = threadIdx.x;
  for (int i = tid; i < MP; i += 256) tokp[i] = -1;
  if (tid == 0) {
    int b = 0, ti = 0;
    for (int e = 0; e < E_NUM; e++) {
      base[e] = b;
      int nt = (counts[e] + BM - 1) / BM;
      for (int j = 0; j < nt; j++) texp[ti++] = e;
      b += nt * BM;
    }
    for (; ti < MAXTILES; ti++) texp[ti] = -1;
  }
}

// ---------------- permutation ----------------
__global__ __launch_bounds__(256) void smoe_perm(
    const int* __restrict__ eid, const int* __restrict__ base,
    int* __restrict__ ctr2, int* __restrict__ tokp)
{
  int t = blockIdx.x * 256 + threadIdx.x;
  if (t < N_TOK) {
    int e = eid[t];
    int r = atomicAdd(&ctr2[e], 1);
    tokp[base[e] + r] = t;
  }
}

// ---------------- transpose-convert fp32 [E][R][C] -> bf16 [E][C][R] ----------------
__global__ __launch_bounds__(256) void smoe_cvt(
    const float* __restrict__ in, unsigned short* __restrict__ out, int R, int C)
{
  int rt = R / 32, ct = C / 32;
  int bid = blockIdx.x;
  int e = bid / (rt * ct);
  int rem = bid % (rt * ct);
  int r0 = (rem / ct) * 32, c0 = (rem % ct) * 32;
  __shared__ float tile[32][33];
  int tx = threadIdx.x & 31, ty = threadIdx.x >> 5;   // ty 0..7
  const float* src = in + (size_t)e * R * C;
#pragma unroll
  for (int i = 0; i < 4; i++)
    tile[ty + 8 * i][tx] = src[(size_t)(r0 + ty + 8 * i) * C + c0 + tx];
  __syncthreads();
  unsigned short* dst = out + (size_t)e * R * C;
#pragma unroll
  for (int i = 0; i < 4; i++)
    dst[(size_t)(c0 + ty + 8 * i) * R + r0 + tx] = f2bf(tile[tx][ty + 8 * i]);
}

// ---------------- GEMM1: h = gelu(xhat_gathered @ W1t^T + b1), bf16 out ----------------
__global__ __launch_bounds__(256) void smoe_gemm1(
    const unsigned short* __restrict__ xhat,   // [N][D]
    const unsigned short* __restrict__ w1t,    // [E][H][D]
    const float* __restrict__ b1,              // [E][H]
    const int* __restrict__ texp,
    const int* __restrict__ tokp,
    unsigned short* __restrict__ hbuf)         // [MP][H]
{
  int mt = blockIdx.x;
  int e = texp[mt];
  if (e < 0) return;
  int nt = blockIdx.y;                 // 0..1 over H
  int tid = threadIdx.x;
  __shared__ unsigned short As[BM * BK];
  __shared__ unsigned short Bs[BN * BK];
  int r = tid >> 2;                    // 0..63
  int c = tid & 3;                     // 16B chunk
  int row0 = mt * BM + r, row1 = row0 + 64;
  int tok0 = tokp[row0]; tok0 = tok0 < 0 ? 0 : tok0;
  int tok1 = tokp[row1]; tok1 = tok1 < 0 ? 0 : tok1;
  const unsigned short* a0 = xhat + (size_t)tok0 * D_DIM + c * 8;
  const unsigned short* a1 = xhat + (size_t)tok1 * D_DIM + c * 8;
  const unsigned short* bb = w1t + (size_t)e * H_DIM * D_DIM
                           + (size_t)(nt * BN + r) * D_DIM + c * 8;
  const unsigned short* bb1 = bb + (size_t)64 * D_DIM;
  unsigned short* As0 = As + r * BK + c * 8;
  unsigned short* As1 = As + (r + 64) * BK + c * 8;
  unsigned short* Bs0 = Bs + r * BK + c * 8;
  unsigned short* Bs1 = Bs + (r + 64) * BK + c * 8;

  int wave = tid >> 6, lane = tid & 63;
  int wr = (wave >> 1) * 64;
  int wc = (wave & 1) * 64;
  int qm = lane & 15;
  int quad = lane >> 4;
  f32x4 acc[4][4] = {};

  for (int k0 = 0; k0 < D_DIM; k0 += BK) {
    gl_lds16(a0 + k0, As0);
    gl_lds16(a1 + k0, As1);
    gl_lds16(bb + k0, Bs0);
    gl_lds16(bb1 + k0, Bs1);
    __syncthreads();
    bf16x8 af[4], bf[4];
#pragma unroll
    for (int i = 0; i < 4; i++) {
      af[i] = *(const bf16x8*)(As + (wr + i * 16 + qm) * BK + quad * 8);
      bf[i] = *(const bf16x8*)(Bs + (wc + i * 16 + qm) * BK + quad * 8);
    }
#pragma unroll
    for (int mi = 0; mi < 4; mi++)
#pragma unroll
      for (int ni = 0; ni < 4; ni++)
        acc[mi][ni] = __builtin_amdgcn_mfma_f32_16x16x32_bf16(
            af[mi], bf[ni], acc[mi][ni], 0, 0, 0);
    __syncthreads();
  }
  int mbase = mt * BM;
#pragma unroll
  for (int ni = 0; ni < 4; ni++) {
    int col = nt * BN + wc + ni * 16 + qm;
    float bias = b1[e * H_DIM + col];
#pragma unroll
    for (int mi = 0; mi < 4; mi++) {
      int rl = wr + mi * 16 + quad * 4;
#pragma unroll
      for (int i = 0; i < 4; i++) {
        float vv = acc[mi][ni][i] + bias;
        float g = 0.5f * vv * (1.0f + erff(vv * 0.70710678118654752f));
        hbuf[(size_t)(mbase + rl + i) * H_DIM + col] = f2bf(g);
      }
    }
  }
}

// ---------------- GEMM2: y[tok] = h @ W2t^T + b2, fp32 scatter ----------------
__global__ __launch_bounds__(256) void smoe_gemm2(
    const unsigned short* __restrict__ hbuf,   // [MP][H]
    const unsigned short* __restrict__ w2t,    // [E][D][H]
    const float* __restrict__ b2,              // [E][D]
    const int* __restrict__ texp,
    const int* __restrict__ tokp,
    float* __restrict__ y)                     // [N][D]
{
  int mt = blockIdx.x;
  int e = texp[mt];
  if (e < 0) return;
  int nt = blockIdx.y;                 // 0..7 over D
  int tid = threadIdx.x;
  __shared__ unsigned short As[BM * BK];
  __shared__ unsigned short Bs[BN * BK];
  int r = tid >> 2;
  int c = tid & 3;
  const unsigned short* a0 = hbuf + (size_t)(mt * BM + r) * H_DIM + c * 8;
  const unsigned short* a1 = a0 + (size_t)64 * H_DIM;
  const unsigned short* bb = w2t + (size_t)e * D_DIM * H_DIM
                           + (size_t)(nt * BN + r) * H_DIM + c * 8;
  const unsigned short* bb1 = bb + (size_t)64 * H_DIM;
  unsigned short* As0 = As + r * BK + c * 8;
  unsigned short* As1 = As + (r + 64) * BK + c * 8;
  unsigned short* Bs0 = Bs + r * BK + c * 8;
  unsigned short* Bs1 = Bs + (r + 64) * BK + c * 8;

  int wave = tid >> 6, lane = tid & 63;
  int wr = (wave >> 1) * 64;
  int wc = (wave & 1) * 64;
  int qm = lane & 15;
  int quad = lane >> 4;
  f32x4 acc[4][4] = {};

  for (int k0 = 0; k0 < H_DIM; k0 += BK) {   // 8 steps
    gl_lds16(a0 + k0, As0);
    gl_lds16(a1 + k0, As1);
    gl_lds16(bb + k0, Bs0);
    gl_lds16(bb1 + k0, Bs1);
    __syncthreads();
    bf16x8 af[4], bf[4];
#pragma unroll
    for (int i = 0; i < 4; i++) {
      af[i] = *(const bf16x8*)(As + (wr + i * 16 + qm) * BK + quad * 8);
      bf[i] = *(const bf16x8*)(Bs + (wc + i * 16 + qm) * BK + quad * 8);
    }
#pragma unroll
    for (int mi = 0; mi < 4; mi++)
#pragma unroll
      for (int ni = 0; ni < 4; ni++)
        acc[mi][ni] = __builtin_amdgcn_mfma_f32_16x16x32_bf16(
            af[mi], bf[ni], acc[mi][ni], 0, 0, 0);
    __syncthreads();
  }
  int mbase = mt * BM;
#pragma unroll
  for (int mi = 0; mi < 4; mi++) {
#pragma unroll
    for (int i = 0; i < 4; i++) {
      int row = mbase + wr + mi * 16 + quad * 4 + i;
      int tok = tokp[row];
      if (tok < 0) continue;
#pragma unroll
      for (int ni = 0; ni < 4; ni++) {
        int col = nt * BN + wc + ni * 16 + qm;
        y[(size_t)tok * D_DIM + col] = acc[mi][ni][i] + b2[e * D_DIM + col];
      }
    }
  }
}

extern "C" void kernel_launch(void* const* d_in, const int* in_sizes, int n_in,
                              void* d_out, int out_size, void* d_ws, size_t ws_size,
                              hipStream_t stream) {
  (void)in_sizes; (void)n_in; (void)out_size; (void)ws_size;
  const float* x    = (const float*)d_in[0];
  const float* wg   = (const float*)d_in[1];
  const float* ln_s = (const float*)d_in[2];
  const float* ln_b = (const float*)d_in[3];
  const float* w1   = (const float*)d_in[4];
  const float* b1   = (const float*)d_in[5];
  const float* w2   = (const float*)d_in[6];
  const float* b2   = (const float*)d_in[7];
  float* y = (float*)d_out;

  char* ws = (char*)d_ws;
  size_t off = 0;
  auto alloc = [&](size_t bytes) {
    void* p = ws + off;
    off = (off + bytes + 255) & ~(size_t)255;
    return p;
  };
  unsigned short* xhat = (unsigned short*)alloc((size_t)N_TOK * D_DIM * 2);          // 32 MB
  unsigned short* w1t  = (unsigned short*)alloc((size_t)E_NUM * D_DIM * H_DIM * 2);  // 4 MB
  unsigned short* w2t  = (unsigned short*)alloc((size_t)E_NUM * D_DIM * H_DIM * 2);  // 4 MB
  unsigned short* hbuf = (unsigned short*)alloc((size_t)MP * H_DIM * 2);             // 8.5 MB
  int* eid    = (int*)alloc((size_t)N_TOK * 4);
  int* tokp   = (int*)alloc((size_t)MP * 4);
  int* counts = (int*)alloc((size_t)E_NUM * 4 * 2);   // counts + ctr2, zeroed below
  int* ctr2   = counts + E_NUM;
  int* base   = (int*)alloc((size_t)E_NUM * 4);
  int* texp   = (int*)alloc((size_t)MAXTILES * 4);

  hipMemsetAsync(counts, 0, E_NUM * 4 * 2, stream);
  smoe_gate<<<N_TOK / 4, 256, 0, stream>>>(x, wg, ln_s, ln_b, xhat, eid, counts);
  smoe_scan<<<1, 256, 0, stream>>>(counts, base, texp, tokp);
  smoe_perm<<<N_TOK / 256, 256, 0, stream>>>(eid, base, ctr2, tokp);
  smoe_cvt<<<E_NUM * (D_DIM / 32) * (H_DIM / 32), 256, 0, stream>>>(w1, w1t, D_DIM, H_DIM);
  smoe_cvt<<<E_NUM * (H_DIM / 32) * (D_DIM / 32), 256, 0, stream>>>(w2, w2t, H_DIM, D_DIM);
  smoe_gemm1<<<dim3(MAXTILES, H_DIM / BN), 256, 0, stream>>>(xhat, w1t, b1, texp, tokp, hbuf);
  smoe_gemm2<<<dim3(MAXTILES, D_DIM / BN), 256, 0, stream>>>(hbuf, w2t, b2, texp, tokp, y);
}

// Round 2
// 442.496 us; speedup vs baseline: 1.0065x; 1.0065x over previous
//
#include <hip/hip_runtime.h>
#include <hip/hip_bf16.h>
#include <math.h>

#define N_TOK 16384
#define D_DIM 1024
#define E_NUM 8
#define H_DIM 256
#define LN_EPS 1e-5f

#define BM 128
#define BN 128
#define BK 32
#define MAXTILES (N_TOK / BM + E_NUM)   /* 136 */
#define MP (MAXTILES * BM)              /* 17408 */

#define TPB_TOK 2   /* tokens per gate block: reuses wg loads across tokens */

typedef __attribute__((ext_vector_type(8))) short bf16x8;
typedef __attribute__((ext_vector_type(4))) float f32x4;

__device__ __forceinline__ unsigned short f2bf(float f) {
  union { float f; unsigned u; } cv; cv.f = f;
  unsigned u = cv.u;
  u += 0x7fffu + ((u >> 16) & 1u);   // round-to-nearest-even
  return (unsigned short)(u >> 16);
}

__device__ __forceinline__ void gl_lds16(const void* g, void* l) {
  __builtin_amdgcn_global_load_lds(
      (const __attribute__((address_space(1))) unsigned int*)g,
      (__attribute__((address_space(3))) unsigned int*)l, 16, 0, 0);
}

// ---------------- gate + layernorm: one block per TPB_TOK tokens ----------------
// Each thread: 1 float4 of x per token, 8 float4 of wg (L1-hot).
// fp64 logit partials -> reduce-scatter butterfly (exact argmax),
// fp32 LN stats -> butterfly. Small per-thread working set => deep MLP.
__global__ __launch_bounds__(256) void smoe_gate(
    const float* __restrict__ x, const float* __restrict__ wg,
    const float* __restrict__ ln_s, const float* __restrict__ ln_b,
    unsigned short* __restrict__ xhat, int* __restrict__ eid,
    int* __restrict__ counts)
{
  int t0 = blockIdx.x * TPB_TOK;
  int tid = threadIdx.x;
  int lane = tid & 63, wave = tid >> 6;

  const float4* x4 = (const float4*)x;
  float4 v[TPB_TOK];
  float s[TPB_TOK], ss[TPB_TOK];
  double lg[TPB_TOK][E_NUM];
#pragma unroll
  for (int u = 0; u < TPB_TOK; u++) {
    v[u] = x4[(size_t)(t0 + u) * 256 + tid];
    s[u]  = v[u].x + v[u].y + v[u].z + v[u].w;
    ss[u] = v[u].x * v[u].x + v[u].y * v[u].y + v[u].z * v[u].z + v[u].w * v[u].w;
  }
  const float4* wg4 = (const float4*)wg;
#pragma unroll
  for (int e = 0; e < E_NUM; e++) {
    float4 w = wg4[e * 256 + tid];
#pragma unroll
    for (int u = 0; u < TPB_TOK; u++)
      lg[u][e] = (double)v[u].x * w.x + (double)v[u].y * w.y
               + (double)v[u].z * w.z + (double)v[u].w * w.w;
  }

  __shared__ double sums[TPB_TOK][4][E_NUM];
  __shared__ float  wst[TPB_TOK][4][2];
  __shared__ float  bc[TPB_TOK][3];

#pragma unroll
  for (int u = 0; u < TPB_TOK; u++) {
    // reduce-scatter: 8 fp64 accumulators -> 1 per lane (expert = lane&7)
    double a0, a1, a2, a3;
    {
      double p0 = __shfl_xor(lg[u][0], 1, 64), p1 = __shfl_xor(lg[u][1], 1, 64);
      double p2 = __shfl_xor(lg[u][2], 1, 64), p3 = __shfl_xor(lg[u][3], 1, 64);
      double p4 = __shfl_xor(lg[u][4], 1, 64), p5 = __shfl_xor(lg[u][5], 1, 64);
      double p6 = __shfl_xor(lg[u][6], 1, 64), p7 = __shfl_xor(lg[u][7], 1, 64);
      bool b = lane & 1;
      a0 = b ? lg[u][1] + p1 : lg[u][0] + p0;
      a1 = b ? lg[u][3] + p3 : lg[u][2] + p2;
      a2 = b ? lg[u][5] + p5 : lg[u][4] + p4;
      a3 = b ? lg[u][7] + p7 : lg[u][6] + p6;
    }
    double c0, c1;
    {
      double q0 = __shfl_xor(a0, 2, 64), q1 = __shfl_xor(a1, 2, 64);
      double q2 = __shfl_xor(a2, 2, 64), q3 = __shfl_xor(a3, 2, 64);
      bool b = (lane >> 1) & 1;
      c0 = b ? a1 + q1 : a0 + q0;
      c1 = b ? a3 + q3 : a2 + q2;
    }
    double c;
    {
      double r0 = __shfl_xor(c0, 4, 64), r1 = __shfl_xor(c1, 4, 64);
      bool b = (lane >> 2) & 1;
      c = b ? c1 + r1 : c0 + r0;
    }
    c += __shfl_xor(c, 8, 64);
    c += __shfl_xor(c, 16, 64);
    c += __shfl_xor(c, 32, 64);
    if (lane < E_NUM) sums[u][wave][lane] = c;

    float sv = s[u], ssv = ss[u];
#pragma unroll
    for (int m = 1; m < 64; m <<= 1) {
      sv  += __shfl_xor(sv, m, 64);
      ssv += __shfl_xor(ssv, m, 64);
    }
    if (lane == 0) { wst[u][wave][0] = sv; wst[u][wave][1] = ssv; }
  }
  __syncthreads();

  if (wave == 0 && lane < E_NUM) {
#pragma unroll
    for (int u = 0; u < TPB_TOK; u++) {
      double tot = sums[u][0][lane] + sums[u][1][lane]
                 + sums[u][2][lane] + sums[u][3][lane];
      double val = tot; int idx = lane;
#pragma unroll
      for (int m = 1; m < E_NUM; m <<= 1) {
        double ov = __shfl_xor(val, m, 64);
        int    oi = __shfl_xor(idx, m, 64);
        if (ov > val || (ov == val && oi < idx)) { val = ov; idx = oi; }  // first-max
      }
      if (lane == 0) {
        float st  = wst[u][0][0] + wst[u][1][0] + wst[u][2][0] + wst[u][3][0];
        float sst = wst[u][0][1] + wst[u][1][1] + wst[u][2][1] + wst[u][3][1];
        float mean = st * (1.0f / (float)D_DIM);
        float var  = sst * (1.0f / (float)D_DIM) - mean * mean;
        float rstd = 1.0f / sqrtf(var + LN_EPS);
        bc[u][0] = (float)idx; bc[u][1] = mean; bc[u][2] = rstd;
        eid[t0 + u] = idx;
        atomicAdd(&counts[idx], 1);
      }
    }
  }
  __syncthreads();

#pragma unroll
  for (int u = 0; u < TPB_TOK; u++) {
    int best = (int)bc[u][0];
    float mean = bc[u][1], rstd = bc[u][2];
    float4 sc = ((const float4*)(ln_s + (size_t)best * D_DIM))[tid];
    float4 bi = ((const float4*)(ln_b + (size_t)best * D_DIM))[tid];
    ushort4 o;
    o.x = f2bf((v[u].x - mean) * rstd * sc.x + bi.x);
    o.y = f2bf((v[u].y - mean) * rstd * sc.y + bi.y);
    o.z = f2bf((v[u].z - mean) * rstd * sc.z + bi.z);
    o.w = f2bf((v[u].w - mean) * rstd * sc.w + bi.w);
    ((ushort4*)(xhat + (size_t)(t0 + u) * D_DIM))[tid] = o;
  }
}

// ---------------- scan: padded segment bases + tile->expert map ----------------
__global__ void smoe_scan(const int* __restrict__ counts, int* __restrict__ base,
                          int* __restrict__ texp, int* __restrict__ tokp)
{
  int tid = threadIdx.x;
  for (int i = tid; i < MP; i += 256) tokp[i] = -1;
  if (tid == 0) {
    int b = 0, ti = 0;
    for (int e = 0; e < E_NUM; e++) {
      base[e] = b;
      int nt = (counts[e] + BM - 1) / BM;
      for (int j = 0; j < nt; j++) texp[ti++] = e;
      b += nt * BM;
    }
    for (; ti < MAXTILES; ti++) texp[ti] = -1;
  }
}

// ---------------- permutation ----------------
__global__ __launch_bounds__(256) void smoe_perm(
    const int* __restrict__ eid, const int* __restrict__ base,
    int* __restrict__ ctr2, int* __restrict__ tokp)
{
  int t = blockIdx.x * 256 + threadIdx.x;
  if (t < N_TOK) {
    int e = eid[t];
    int r = atomicAdd(&ctr2[e], 1);
    tokp[base[e] + r] = t;
  }
}

// ---------------- transpose-convert fp32 [E][R][C] -> bf16 [E][C][R] ----------------
__global__ __launch_bounds__(256) void smoe_cvt(
    const float* __restrict__ in, unsigned short* __restrict__ out, int R, int C)
{
  int rt = R / 32, ct = C / 32;
  int bid = blockIdx.x;
  int e = bid / (rt * ct);
  int rem = bid % (rt * ct);
  int r0 = (rem / ct) * 32, c0 = (rem % ct) * 32;
  __shared__ float tile[32][33];
  int tx = threadIdx.x & 31, ty = threadIdx.x >> 5;   // ty 0..7
  const float* src = in + (size_t)e * R * C;
#pragma unroll
  for (int i = 0; i < 4; i++)
    tile[ty + 8 * i][tx] = src[(size_t)(r0 + ty + 8 * i) * C + c0 + tx];
  __syncthreads();
  unsigned short* dst = out + (size_t)e * R * C;
#pragma unroll
  for (int i = 0; i < 4; i++)
    dst[(size_t)(c0 + ty + 8 * i) * R + r0 + tx] = f2bf(tile[tx][ty + 8 * i]);
}

// ---------------- GEMM1: h = gelu(xhat_gathered @ W1t^T + b1), bf16 out ----------------
__global__ __launch_bounds__(256) void smoe_gemm1(
    const unsigned short* __restrict__ xhat,   // [N][D]
    const unsigned short* __restrict__ w1t,    // [E][H][D]
    const float* __restrict__ b1,              // [E][H]
    const int* __restrict__ texp,
    const int* __restrict__ tokp,
    unsigned short* __restrict__ hbuf)         // [MP][H]
{
  int mt = blockIdx.x;
  int e = texp[mt];
  if (e < 0) return;
  int nt = blockIdx.y;                 // 0..1 over H
  int tid = threadIdx.x;
  __shared__ unsigned short As[BM * BK];
  __shared__ unsigned short Bs[BN * BK];
  int r = tid >> 2;                    // 0..63
  int c = tid & 3;                     // 16B chunk
  int row0 = mt * BM + r, row1 = row0 + 64;
  int tok0 = tokp[row0]; tok0 = tok0 < 0 ? 0 : tok0;
  int tok1 = tokp[row1]; tok1 = tok1 < 0 ? 0 : tok1;
  const unsigned short* a0 = xhat + (size_t)tok0 * D_DIM + c * 8;
  const unsigned short* a1 = xhat + (size_t)tok1 * D_DIM + c * 8;
  const unsigned short* bb = w1t + (size_t)e * H_DIM * D_DIM
                           + (size_t)(nt * BN + r) * D_DIM + c * 8;
  const unsigned short* bb1 = bb + (size_t)64 * D_DIM;
  unsigned short* As0 = As + r * BK + c * 8;
  unsigned short* As1 = As + (r + 64) * BK + c * 8;
  unsigned short* Bs0 = Bs + r * BK + c * 8;
  unsigned short* Bs1 = Bs + (r + 64) * BK + c * 8;

  int wave = tid >> 6, lane = tid & 63;
  int wr = (wave >> 1) * 64;
  int wc = (wave & 1) * 64;
  int qm = lane & 15;
  int quad = lane >> 4;
  f32x4 acc[4][4] = {};

  for (int k0 = 0; k0 < D_DIM; k0 += BK) {
    gl_lds16(a0 + k0, As0);
    gl_lds16(a1 + k0, As1);
    gl_lds16(bb + k0, Bs0);
    gl_lds16(bb1 + k0, Bs1);
    __syncthreads();
    bf16x8 af[4], bf[4];
#pragma unroll
    for (int i = 0; i < 4; i++) {
      af[i] = *(const bf16x8*)(As + (wr + i * 16 + qm) * BK + quad * 8);
      bf[i] = *(const bf16x8*)(Bs + (wc + i * 16 + qm) * BK + quad * 8);
    }
#pragma unroll
    for (int mi = 0; mi < 4; mi++)
#pragma unroll
      for (int ni = 0; ni < 4; ni++)
        acc[mi][ni] = __builtin_amdgcn_mfma_f32_16x16x32_bf16(
            af[mi], bf[ni], acc[mi][ni], 0, 0, 0);
    __syncthreads();
  }
  int mbase = mt * BM;
#pragma unroll
  for (int ni = 0; ni < 4; ni++) {
    int col = nt * BN + wc + ni * 16 + qm;
    float bias = b1[e * H_DIM + col];
#pragma unroll
    for (int mi = 0; mi < 4; mi++) {
      int rl = wr + mi * 16 + quad * 4;
#pragma unroll
      for (int i = 0; i < 4; i++) {
        float vv = acc[mi][ni][i] + bias;
        float g = 0.5f * vv * (1.0f + erff(vv * 0.70710678118654752f));
        hbuf[(size_t)(mbase + rl + i) * H_DIM + col] = f2bf(g);
      }
    }
  }
}

// ---------------- GEMM2: y[tok] = h @ W2t^T + b2, fp32 scatter ----------------
__global__ __launch_bounds__(256) void smoe_gemm2(
    const unsigned short* __restrict__ hbuf,   // [MP][H]
    const unsigned short* __restrict__ w2t,    // [E][D][H]
    const float* __restrict__ b2,              // [E][D]
    const int* __restrict__ texp,
    const int* __restrict__ tokp,
    float* __restrict__ y)                     // [N][D]
{
  int mt = blockIdx.x;
  int e = texp[mt];
  if (e < 0) return;
  int nt = blockIdx.y;                 // 0..7 over D
  int tid = threadIdx.x;
  __shared__ unsigned short As[BM * BK];
  __shared__ unsigned short Bs[BN * BK];
  int r = tid >> 2;
  int c = tid & 3;
  const unsigned short* a0 = hbuf + (size_t)(mt * BM + r) * H_DIM + c * 8;
  const unsigned short* a1 = a0 + (size_t)64 * H_DIM;
  const unsigned short* bb = w2t + (size_t)e * D_DIM * H_DIM
                           + (size_t)(nt * BN + r) * H_DIM + c * 8;
  const unsigned short* bb1 = bb + (size_t)64 * H_DIM;
  unsigned short* As0 = As + r * BK + c * 8;
  unsigned short* As1 = As + (r + 64) * BK + c * 8;
  unsigned short* Bs0 = Bs + r * BK + c * 8;
  unsigned short* Bs1 = Bs + (r + 64) * BK + c * 8;

  int wave = tid >> 6, lane = tid & 63;
  int wr = (wave >> 1) * 64;
  int wc = (wave & 1) * 64;
  int qm = lane & 15;
  int quad = lane >> 4;
  f32x4 acc[4][4] = {};

  for (int k0 = 0; k0 < H_DIM; k0 += BK) {   // 8 steps
    gl_lds16(a0 + k0, As0);
    gl_lds16(a1 + k0, As1);
    gl_lds16(bb + k0, Bs0);
    gl_lds16(bb1 + k0, Bs1);
    __syncthreads();
    bf16x8 af[4], bf[4];
#pragma unroll
    for (int i = 0; i < 4; i++) {
      af[i] = *(const bf16x8*)(As + (wr + i * 16 + qm) * BK + quad * 8);
      bf[i] = *(const bf16x8*)(Bs + (wc + i * 16 + qm) * BK + quad * 8);
    }
#pragma unroll
    for (int mi = 0; mi < 4; mi++)
#pragma unroll
      for (int ni = 0; ni < 4; ni++)
        acc[mi][ni] = __builtin_amdgcn_mfma_f32_16x16x32_bf16(
            af[mi], bf[ni], acc[mi][ni], 0, 0, 0);
    __syncthreads();
  }
  int mbase = mt * BM;
#pragma unroll
  for (int mi = 0; mi < 4; mi++) {
#pragma unroll
    for (int i = 0; i < 4; i++) {
      int row = mbase + wr + mi * 16 + quad * 4 + i;
      int tok = tokp[row];
      if (tok < 0) continue;
#pragma unroll
      for (int ni = 0; ni < 4; ni++) {
        int col = nt * BN + wc + ni * 16 + qm;
        y[(size_t)tok * D_DIM + col] = acc[mi][ni][i] + b2[e * D_DIM + col];
      }
    }
  }
}

extern "C" void kernel_launch(void* const* d_in, const int* in_sizes, int n_in,
                              void* d_out, int out_size, void* d_ws, size_t ws_size,
                              hipStream_t stream) {
  (void)in_sizes; (void)n_in; (void)out_size; (void)ws_size;
  const float* x    = (const float*)d_in[0];
  const float* wg   = (const float*)d_in[1];
  const float* ln_s = (const float*)d_in[2];
  const float* ln_b = (const float*)d_in[3];
  const float* w1   = (const float*)d_in[4];
  const float* b1   = (const float*)d_in[5];
  const float* w2   = (const float*)d_in[6];
  const float* b2   = (const float*)d_in[7];
  float* y = (float*)d_out;

  char* ws = (char*)d_ws;
  size_t off = 0;
  auto alloc = [&](size_t bytes) {
    void* p = ws + off;
    off = (off + bytes + 255) & ~(size_t)255;
    return p;
  };
  unsigned short* xhat = (unsigned short*)alloc((size_t)N_TOK * D_DIM * 2);          // 32 MB
  unsigned short* w1t  = (unsigned short*)alloc((size_t)E_NUM * D_DIM * H_DIM * 2);  // 4 MB
  unsigned short* w2t  = (unsigned short*)alloc((size_t)E_NUM * D_DIM * H_DIM * 2);  // 4 MB
  unsigned short* hbuf = (unsigned short*)alloc((size_t)MP * H_DIM * 2);             // 8.5 MB
  int* eid    = (int*)alloc((size_t)N_TOK * 4);
  int* tokp   = (int*)alloc((size_t)MP * 4);
  int* counts = (int*)alloc((size_t)E_NUM * 4 * 2);   // counts + ctr2, zeroed below
  int* ctr2   = counts + E_NUM;
  int* base   = (int*)alloc((size_t)E_NUM * 4);
  int* texp   = (int*)alloc((size_t)MAXTILES * 4);

  hipMemsetAsync(counts, 0, E_NUM * 4 * 2, stream);
  smoe_gate<<<N_TOK / TPB_TOK, 256, 0, stream>>>(x, wg, ln_s, ln_b, xhat, eid, counts);
  smoe_scan<<<1, 256, 0, stream>>>(counts, base, texp, tokp);
  smoe_perm<<<N_TOK / 256, 256, 0, stream>>>(eid, base, ctr2, tokp);
  smoe_cvt<<<E_NUM * (D_DIM / 32) * (H_DIM / 32), 256, 0, stream>>>(w1, w1t, D_DIM, H_DIM);
  smoe_cvt<<<E_NUM * (H_DIM / 32) * (D_DIM / 32), 256, 0, stream>>>(w2, w2t, H_DIM, D_DIM);
  smoe_gemm1<<<dim3(MAXTILES, H_DIM / BN), 256, 0, stream>>>(xhat, w1t, b1, texp, tokp, hbuf);
  smoe_gemm2<<<dim3(MAXTILES, D_DIM / BN), 256, 0, stream>>>(hbuf, w2t, b2, texp, tokp, y);
}

// Round 3
// 266.204 us; speedup vs baseline: 1.6731x; 1.6622x over previous
//
#include <hip/hip_runtime.h>
#include <hip/hip_bf16.h>
#include <math.h>

#define N_TOK 16384
#define D_DIM 1024
#define E_NUM 8
#define H_DIM 256
#define LN_EPS 1e-5f

#define BM 128
#define BN 128
#define BK 32
#define MAXTILES (N_TOK / BM + E_NUM)   /* 136 */
#define MP (MAXTILES * BM)              /* 17408 */

#define TPB_TOK 2   /* tokens per gate block */

typedef __attribute__((ext_vector_type(8))) short bf16x8;
typedef __attribute__((ext_vector_type(4))) float f32x4;

__device__ __forceinline__ unsigned short f2bf(float f) {
  union { float f; unsigned u; } cv; cv.f = f;
  unsigned u = cv.u;
  u += 0x7fffu + ((u >> 16) & 1u);   // round-to-nearest-even
  return (unsigned short)(u >> 16);
}

__device__ __forceinline__ void gl_lds16(const void* g, void* l) {
  __builtin_amdgcn_global_load_lds(
      (const __attribute__((address_space(1))) unsigned int*)g,
      (__attribute__((address_space(3))) unsigned int*)l, 16, 0, 0);
}

// ---------------- gate + layernorm: one block per TPB_TOK tokens ----------------
// NO global atomics (the 16384 same-cacheline atomicAdds were the 203us wall).
__global__ __launch_bounds__(256) void smoe_gate(
    const float* __restrict__ x, const float* __restrict__ wg,
    const float* __restrict__ ln_s, const float* __restrict__ ln_b,
    unsigned short* __restrict__ xhat, int* __restrict__ eid)
{
  int t0 = blockIdx.x * TPB_TOK;
  int tid = threadIdx.x;
  int lane = tid & 63, wave = tid >> 6;

  const float4* x4 = (const float4*)x;
  float4 v[TPB_TOK];
  float s[TPB_TOK], ss[TPB_TOK];
  double lg[TPB_TOK][E_NUM];
#pragma unroll
  for (int u = 0; u < TPB_TOK; u++) {
    v[u] = x4[(size_t)(t0 + u) * 256 + tid];
    s[u]  = v[u].x + v[u].y + v[u].z + v[u].w;
    ss[u] = v[u].x * v[u].x + v[u].y * v[u].y + v[u].z * v[u].z + v[u].w * v[u].w;
  }
  const float4* wg4 = (const float4*)wg;
#pragma unroll
  for (int e = 0; e < E_NUM; e++) {
    float4 w = wg4[e * 256 + tid];
#pragma unroll
    for (int u = 0; u < TPB_TOK; u++)
      lg[u][e] = (double)v[u].x * w.x + (double)v[u].y * w.y
               + (double)v[u].z * w.z + (double)v[u].w * w.w;
  }

  __shared__ double sums[TPB_TOK][4][E_NUM];
  __shared__ float  wst[TPB_TOK][4][2];
  __shared__ float  bc[TPB_TOK][3];

#pragma unroll
  for (int u = 0; u < TPB_TOK; u++) {
    // reduce-scatter: 8 fp64 accumulators -> 1 per lane (expert = lane&7)
    double a0, a1, a2, a3;
    {
      double p0 = __shfl_xor(lg[u][0], 1, 64), p1 = __shfl_xor(lg[u][1], 1, 64);
      double p2 = __shfl_xor(lg[u][2], 1, 64), p3 = __shfl_xor(lg[u][3], 1, 64);
      double p4 = __shfl_xor(lg[u][4], 1, 64), p5 = __shfl_xor(lg[u][5], 1, 64);
      double p6 = __shfl_xor(lg[u][6], 1, 64), p7 = __shfl_xor(lg[u][7], 1, 64);
      bool b = lane & 1;
      a0 = b ? lg[u][1] + p1 : lg[u][0] + p0;
      a1 = b ? lg[u][3] + p3 : lg[u][2] + p2;
      a2 = b ? lg[u][5] + p5 : lg[u][4] + p4;
      a3 = b ? lg[u][7] + p7 : lg[u][6] + p6;
    }
    double c0, c1;
    {
      double q0 = __shfl_xor(a0, 2, 64), q1 = __shfl_xor(a1, 2, 64);
      double q2 = __shfl_xor(a2, 2, 64), q3 = __shfl_xor(a3, 2, 64);
      bool b = (lane >> 1) & 1;
      c0 = b ? a1 + q1 : a0 + q0;
      c1 = b ? a3 + q3 : a2 + q2;
    }
    double c;
    {
      double r0 = __shfl_xor(c0, 4, 64), r1 = __shfl_xor(c1, 4, 64);
      bool b = (lane >> 2) & 1;
      c = b ? c1 + r1 : c0 + r0;
    }
    c += __shfl_xor(c, 8, 64);
    c += __shfl_xor(c, 16, 64);
    c += __shfl_xor(c, 32, 64);
    if (lane < E_NUM) sums[u][wave][lane] = c;

    float sv = s[u], ssv = ss[u];
#pragma unroll
    for (int m = 1; m < 64; m <<= 1) {
      sv  += __shfl_xor(sv, m, 64);
      ssv += __shfl_xor(ssv, m, 64);
    }
    if (lane == 0) { wst[u][wave][0] = sv; wst[u][wave][1] = ssv; }
  }
  __syncthreads();

  if (wave == 0 && lane < E_NUM) {
#pragma unroll
    for (int u = 0; u < TPB_TOK; u++) {
      double tot = sums[u][0][lane] + sums[u][1][lane]
                 + sums[u][2][lane] + sums[u][3][lane];
      double val = tot; int idx = lane;
#pragma unroll
      for (int m = 1; m < E_NUM; m <<= 1) {
        double ov = __shfl_xor(val, m, 64);
        int    oi = __shfl_xor(idx, m, 64);
        if (ov > val || (ov == val && oi < idx)) { val = ov; idx = oi; }  // first-max
      }
      if (lane == 0) {
        float st  = wst[u][0][0] + wst[u][1][0] + wst[u][2][0] + wst[u][3][0];
        float sst = wst[u][0][1] + wst[u][1][1] + wst[u][2][1] + wst[u][3][1];
        float mean = st * (1.0f / (float)D_DIM);
        float var  = sst * (1.0f / (float)D_DIM) - mean * mean;
        float rstd = 1.0f / sqrtf(var + LN_EPS);
        bc[u][0] = (float)idx; bc[u][1] = mean; bc[u][2] = rstd;
        eid[t0 + u] = idx;
      }
    }
  }
  __syncthreads();

#pragma unroll
  for (int u = 0; u < TPB_TOK; u++) {
    int best = (int)bc[u][0];
    float mean = bc[u][1], rstd = bc[u][2];
    float4 sc = ((const float4*)(ln_s + (size_t)best * D_DIM))[tid];
    float4 bi = ((const float4*)(ln_b + (size_t)best * D_DIM))[tid];
    ushort4 o;
    o.x = f2bf((v[u].x - mean) * rstd * sc.x + bi.x);
    o.y = f2bf((v[u].y - mean) * rstd * sc.y + bi.y);
    o.z = f2bf((v[u].z - mean) * rstd * sc.z + bi.z);
    o.w = f2bf((v[u].w - mean) * rstd * sc.w + bi.w);
    ((ushort4*)(xhat + (size_t)(t0 + u) * D_DIM))[tid] = o;
  }
}

// ---------------- route: histogram + scan + permutation, ZERO global atomics ----
// One block, 1024 threads, 16 tokens/thread. Register histograms (constant-
// indexed), Kogge-Stone wave scan, cross-wave scan via LDS, deterministic ranks.
__global__ __launch_bounds__(1024) void smoe_route(
    const int* __restrict__ eid, int* __restrict__ texp, int* __restrict__ tokp)
{
  int tid = threadIdx.x;
  int lane = tid & 63, wave = tid >> 6;   // 16 waves

  int cnt[E_NUM] = {};
  int ee[16];
#pragma unroll
  for (int j = 0; j < 16; j++) {
    int e = eid[j * 1024 + tid];
    ee[j] = e;
#pragma unroll
    for (int k = 0; k < E_NUM; k++) cnt[k] += (e == k);
  }
  // inclusive Kogge-Stone scan within wave, per counter
  int inc[E_NUM];
#pragma unroll
  for (int k = 0; k < E_NUM; k++) inc[k] = cnt[k];
#pragma unroll
  for (int m = 1; m < 64; m <<= 1) {
#pragma unroll
    for (int k = 0; k < E_NUM; k++) {
      int o = __shfl_up(inc[k], m, 64);
      if (lane >= m) inc[k] += o;
    }
  }
  __shared__ int wtot[16][E_NUM];
  __shared__ int wbase[16][E_NUM];
  __shared__ int ebase[E_NUM];
  __shared__ int ecnt[E_NUM];
  __shared__ int epad[E_NUM];
  if (lane == 63)
#pragma unroll
    for (int k = 0; k < E_NUM; k++) wtot[wave][k] = inc[k];
  __syncthreads();
  if (tid == 0) {
    int run[E_NUM] = {};
    for (int w = 0; w < 16; w++)
#pragma unroll
      for (int k = 0; k < E_NUM; k++) { wbase[w][k] = run[k]; run[k] += wtot[w][k]; }
    int b = 0, ti = 0;
    for (int k = 0; k < E_NUM; k++) {
      ecnt[k] = run[k];
      ebase[k] = b;
      int nt = (run[k] + BM - 1) / BM;
      for (int j = 0; j < nt; j++) texp[ti++] = k;
      epad[k] = nt * BM;
      b += nt * BM;
    }
    for (; ti < MAXTILES; ti++) texp[ti] = -1;
  }
  __syncthreads();
  // exclusive per-thread base per expert
  int tb[E_NUM];
#pragma unroll
  for (int k = 0; k < E_NUM; k++) tb[k] = wbase[wave][k] + inc[k] - cnt[k];
  int run2[E_NUM] = {};
#pragma unroll
  for (int j = 0; j < 16; j++) {
    int e = ee[j];
    int r = 0;
#pragma unroll
    for (int k = 0; k < E_NUM; k++) {
      if (e == k) r = tb[k] + run2[k];
      run2[k] += (e == k);
    }
    tokp[ebase[e] + r] = j * 1024 + tid;
  }
  // fill pad slots with -1 (disjoint from rank slots; no sync needed)
#pragma unroll
  for (int k = 0; k < E_NUM; k++) {
    int s0 = ebase[k] + ecnt[k], n = epad[k] - ecnt[k];
    for (int i = tid; i < n; i += 1024) tokp[s0 + i] = -1;
  }
}

// ---------------- transpose-convert fp32 [E][R][C] -> bf16 [E][C][R] ----------------
__global__ __launch_bounds__(256) void smoe_cvt(
    const float* __restrict__ in, unsigned short* __restrict__ out, int R, int C)
{
  int rt = R / 32, ct = C / 32;
  int bid = blockIdx.x;
  int e = bid / (rt * ct);
  int rem = bid % (rt * ct);
  int r0 = (rem / ct) * 32, c0 = (rem % ct) * 32;
  __shared__ float tile[32][33];
  int tx = threadIdx.x & 31, ty = threadIdx.x >> 5;   // ty 0..7
  const float* src = in + (size_t)e * R * C;
#pragma unroll
  for (int i = 0; i < 4; i++)
    tile[ty + 8 * i][tx] = src[(size_t)(r0 + ty + 8 * i) * C + c0 + tx];
  __syncthreads();
  unsigned short* dst = out + (size_t)e * R * C;
#pragma unroll
  for (int i = 0; i < 4; i++)
    dst[(size_t)(c0 + ty + 8 * i) * R + r0 + tx] = f2bf(tile[tx][ty + 8 * i]);
}

// ---------------- GEMM1: h = gelu(xhat_gathered @ W1t^T + b1), bf16 out ----------------
__global__ __launch_bounds__(256) void smoe_gemm1(
    const unsigned short* __restrict__ xhat,   // [N][D]
    const unsigned short* __restrict__ w1t,    // [E][H][D]
    const float* __restrict__ b1,              // [E][H]
    const int* __restrict__ texp,
    const int* __restrict__ tokp,
    unsigned short* __restrict__ hbuf)         // [MP][H]
{
  int mt = blockIdx.x;
  int e = texp[mt];
  if (e < 0) return;
  int nt = blockIdx.y;                 // 0..1 over H
  int tid = threadIdx.x;
  __shared__ unsigned short As[BM * BK];
  __shared__ unsigned short Bs[BN * BK];
  int r = tid >> 2;                    // 0..63
  int c = tid & 3;                     // 16B chunk
  int row0 = mt * BM + r, row1 = row0 + 64;
  int tok0 = tokp[row0]; tok0 = tok0 < 0 ? 0 : tok0;
  int tok1 = tokp[row1]; tok1 = tok1 < 0 ? 0 : tok1;
  const unsigned short* a0 = xhat + (size_t)tok0 * D_DIM + c * 8;
  const unsigned short* a1 = xhat + (size_t)tok1 * D_DIM + c * 8;
  const unsigned short* bb = w1t + (size_t)e * H_DIM * D_DIM
                           + (size_t)(nt * BN + r) * D_DIM + c * 8;
  const unsigned short* bb1 = bb + (size_t)64 * D_DIM;
  unsigned short* As0 = As + r * BK + c * 8;
  unsigned short* As1 = As + (r + 64) * BK + c * 8;
  unsigned short* Bs0 = Bs + r * BK + c * 8;
  unsigned short* Bs1 = Bs + (r + 64) * BK + c * 8;

  int wave = tid >> 6, lane = tid & 63;
  int wr = (wave >> 1) * 64;
  int wc = (wave & 1) * 64;
  int qm = lane & 15;
  int quad = lane >> 4;
  f32x4 acc[4][4] = {};

  for (int k0 = 0; k0 < D_DIM; k0 += BK) {
    gl_lds16(a0 + k0, As0);
    gl_lds16(a1 + k0, As1);
    gl_lds16(bb + k0, Bs0);
    gl_lds16(bb1 + k0, Bs1);
    __syncthreads();
    bf16x8 af[4], bf[4];
#pragma unroll
    for (int i = 0; i < 4; i++) {
      af[i] = *(const bf16x8*)(As + (wr + i * 16 + qm) * BK + quad * 8);
      bf[i] = *(const bf16x8*)(Bs + (wc + i * 16 + qm) * BK + quad * 8);
    }
#pragma unroll
    for (int mi = 0; mi < 4; mi++)
#pragma unroll
      for (int ni = 0; ni < 4; ni++)
        acc[mi][ni] = __builtin_amdgcn_mfma_f32_16x16x32_bf16(
            af[mi], bf[ni], acc[mi][ni], 0, 0, 0);
    __syncthreads();
  }
  int mbase = mt * BM;
#pragma unroll
  for (int ni = 0; ni < 4; ni++) {
    int col = nt * BN + wc + ni * 16 + qm;
    float bias = b1[e * H_DIM + col];
#pragma unroll
    for (int mi = 0; mi < 4; mi++) {
      int rl = wr + mi * 16 + quad * 4;
#pragma unroll
      for (int i = 0; i < 4; i++) {
        float vv = acc[mi][ni][i] + bias;
        float g = 0.5f * vv * (1.0f + erff(vv * 0.70710678118654752f));
        hbuf[(size_t)(mbase + rl + i) * H_DIM + col] = f2bf(g);
      }
    }
  }
}

// ---------------- GEMM2: y[tok] = h @ W2t^T + b2, fp32 scatter ----------------
__global__ __launch_bounds__(256) void smoe_gemm2(
    const unsigned short* __restrict__ hbuf,   // [MP][H]
    const unsigned short* __restrict__ w2t,    // [E][D][H]
    const float* __restrict__ b2,              // [E][D]
    const int* __restrict__ texp,
    const int* __restrict__ tokp,
    float* __restrict__ y)                     // [N][D]
{
  int mt = blockIdx.x;
  int e = texp[mt];
  if (e < 0) return;
  int nt = blockIdx.y;                 // 0..7 over D
  int tid = threadIdx.x;
  __shared__ unsigned short As[BM * BK];
  __shared__ unsigned short Bs[BN * BK];
  int r = tid >> 2;
  int c = tid & 3;
  const unsigned short* a0 = hbuf + (size_t)(mt * BM + r) * H_DIM + c * 8;
  const unsigned short* a1 = a0 + (size_t)64 * H_DIM;
  const unsigned short* bb = w2t + (size_t)e * D_DIM * H_DIM
                           + (size_t)(nt * BN + r) * H_DIM + c * 8;
  const unsigned short* bb1 = bb + (size_t)64 * H_DIM;
  unsigned short* As0 = As + r * BK + c * 8;
  unsigned short* As1 = As + (r + 64) * BK + c * 8;
  unsigned short* Bs0 = Bs + r * BK + c * 8;
  unsigned short* Bs1 = Bs + (r + 64) * BK + c * 8;

  int wave = tid >> 6, lane = tid & 63;
  int wr = (wave >> 1) * 64;
  int wc = (wave & 1) * 64;
  int qm = lane & 15;
  int quad = lane >> 4;
  f32x4 acc[4][4] = {};

  for (int k0 = 0; k0 < H_DIM; k0 += BK) {   // 8 steps
    gl_lds16(a0 + k0, As0);
    gl_lds16(a1 + k0, As1);
    gl_lds16(bb + k0, Bs0);
    gl_lds16(bb1 + k0, Bs1);
    __syncthreads();
    bf16x8 af[4], bf[4];
#pragma unroll
    for (int i = 0; i < 4; i++) {
      af[i] = *(const bf16x8*)(As + (wr + i * 16 + qm) * BK + quad * 8);
      bf[i] = *(const bf16x8*)(Bs + (wc + i * 16 + qm) * BK + quad * 8);
    }
#pragma unroll
    for (int mi = 0; mi < 4; mi++)
#pragma unroll
      for (int ni = 0; ni < 4; ni++)
        acc[mi][ni] = __builtin_amdgcn_mfma_f32_16x16x32_bf16(
            af[mi], bf[ni], acc[mi][ni], 0, 0, 0);
    __syncthreads();
  }
  int mbase = mt * BM;
#pragma unroll
  for (int mi = 0; mi < 4; mi++) {
#pragma unroll
    for (int i = 0; i < 4; i++) {
      int row = mbase + wr + mi * 16 + quad * 4 + i;
      int tok = tokp[row];
      if (tok < 0) continue;
#pragma unroll
      for (int ni = 0; ni < 4; ni++) {
        int col = nt * BN + wc + ni * 16 + qm;
        y[(size_t)tok * D_DIM + col] = acc[mi][ni][i] + b2[e * D_DIM + col];
      }
    }
  }
}

extern "C" void kernel_launch(void* const* d_in, const int* in_sizes, int n_in,
                              void* d_out, int out_size, void* d_ws, size_t ws_size,
                              hipStream_t stream) {
  (void)in_sizes; (void)n_in; (void)out_size; (void)ws_size;
  const float* x    = (const float*)d_in[0];
  const float* wg   = (const float*)d_in[1];
  const float* ln_s = (const float*)d_in[2];
  const float* ln_b = (const float*)d_in[3];
  const float* w1   = (const float*)d_in[4];
  const float* b1   = (const float*)d_in[5];
  const float* w2   = (const float*)d_in[6];
  const float* b2   = (const float*)d_in[7];
  float* y = (float*)d_out;

  char* ws = (char*)d_ws;
  size_t off = 0;
  auto alloc = [&](size_t bytes) {
    void* p = ws + off;
    off = (off + bytes + 255) & ~(size_t)255;
    return p;
  };
  unsigned short* xhat = (unsigned short*)alloc((size_t)N_TOK * D_DIM * 2);          // 32 MB
  unsigned short* w1t  = (unsigned short*)alloc((size_t)E_NUM * D_DIM * H_DIM * 2);  // 4 MB
  unsigned short* w2t  = (unsigned short*)alloc((size_t)E_NUM * D_DIM * H_DIM * 2);  // 4 MB
  unsigned short* hbuf = (unsigned short*)alloc((size_t)MP * H_DIM * 2);             // 8.5 MB
  int* eid    = (int*)alloc((size_t)N_TOK * 4);
  int* tokp   = (int*)alloc((size_t)MP * 4);
  int* texp   = (int*)alloc((size_t)MAXTILES * 4);

  smoe_gate<<<N_TOK / TPB_TOK, 256, 0, stream>>>(x, wg, ln_s, ln_b, xhat, eid);
  smoe_route<<<1, 1024, 0, stream>>>(eid, texp, tokp);
  smoe_cvt<<<E_NUM * (D_DIM / 32) * (H_DIM / 32), 256, 0, stream>>>(w1, w1t, D_DIM, H_DIM);
  smoe_cvt<<<E_NUM * (H_DIM / 32) * (D_DIM / 32), 256, 0, stream>>>(w2, w2t, H_DIM, D_DIM);
  smoe_gemm1<<<dim3(MAXTILES, H_DIM / BN), 256, 0, stream>>>(xhat, w1t, b1, texp, tokp, hbuf);
  smoe_gemm2<<<dim3(MAXTILES, D_DIM / BN), 256, 0, stream>>>(hbuf, w2t, b2, texp, tokp, y);
}

// Round 4
// 258.382 us; speedup vs baseline: 1.7237x; 1.0303x over previous
//
#include <hip/hip_runtime.h>
#include <hip/hip_bf16.h>
#include <math.h>

#define N_TOK 16384
#define D_DIM 1024
#define E_NUM 8
#define H_DIM 256
#define LN_EPS 1e-5f

#define BM 128
#define BN 128
#define BN1 64
#define BK 32
#define MAXTILES (N_TOK / BM + E_NUM)   /* 136 */
#define MP (MAXTILES * BM)              /* 17408 */

#define TPB_TOK 2   /* tokens per gate block */

typedef __attribute__((ext_vector_type(8))) short bf16x8;
typedef __attribute__((ext_vector_type(4))) float f32x4;

__device__ __forceinline__ unsigned short f2bf(float f) {
  union { float f; unsigned u; } cv; cv.f = f;
  unsigned u = cv.u;
  u += 0x7fffu + ((u >> 16) & 1u);   // round-to-nearest-even
  return (unsigned short)(u >> 16);
}

__device__ __forceinline__ void gl_lds16(const void* g, void* l) {
  __builtin_amdgcn_global_load_lds(
      (const __attribute__((address_space(1))) unsigned int*)g,
      (__attribute__((address_space(3))) unsigned int*)l, 16, 0, 0);
}

// ---------------- gate + layernorm: one block per TPB_TOK tokens ----------------
// fp64 logits for exact argmax. Reduction: 3 shuffle stages (8->1 per lane),
// then LDS combine (no long fp64 butterfly tails, no serialized wave0 section).
__global__ __launch_bounds__(256) void smoe_gate(
    const float* __restrict__ x, const float* __restrict__ wg,
    const float* __restrict__ ln_s, const float* __restrict__ ln_b,
    unsigned short* __restrict__ xhat, int* __restrict__ eid)
{
  int t0 = blockIdx.x * TPB_TOK;
  int tid = threadIdx.x;
  int lane = tid & 63, wave = tid >> 6;

  const float4* x4 = (const float4*)x;
  float4 v[TPB_TOK];
  float s[TPB_TOK], ss[TPB_TOK];
  double lg[TPB_TOK][E_NUM];
#pragma unroll
  for (int u = 0; u < TPB_TOK; u++) {
    v[u] = x4[(size_t)(t0 + u) * 256 + tid];
    s[u]  = v[u].x + v[u].y + v[u].z + v[u].w;
    ss[u] = v[u].x * v[u].x + v[u].y * v[u].y + v[u].z * v[u].z + v[u].w * v[u].w;
  }
  const float4* wg4 = (const float4*)wg;
#pragma unroll
  for (int e = 0; e < E_NUM; e++) {
    float4 w = wg4[e * 256 + tid];
#pragma unroll
    for (int u = 0; u < TPB_TOK; u++)
      lg[u][e] = (double)v[u].x * w.x + (double)v[u].y * w.y
               + (double)v[u].z * w.z + (double)v[u].w * w.w;
  }

  __shared__ double lred[TPB_TOK][4][64];   // 4 KB
  __shared__ float  wst[TPB_TOK][4][2];
  __shared__ double etot[TPB_TOK][E_NUM];
  __shared__ float  stot[TPB_TOK][2];

#pragma unroll
  for (int u = 0; u < TPB_TOK; u++) {
    // reduce-scatter: 8 fp64 accumulators -> 1 per lane (expert = lane&7,
    // summed over the lane's 8-lane group g = lane>>3)
    double a0, a1, a2, a3;
    {
      double p0 = __shfl_xor(lg[u][0], 1, 64), p1 = __shfl_xor(lg[u][1], 1, 64);
      double p2 = __shfl_xor(lg[u][2], 1, 64), p3 = __shfl_xor(lg[u][3], 1, 64);
      double p4 = __shfl_xor(lg[u][4], 1, 64), p5 = __shfl_xor(lg[u][5], 1, 64);
      double p6 = __shfl_xor(lg[u][6], 1, 64), p7 = __shfl_xor(lg[u][7], 1, 64);
      bool b = lane & 1;
      a0 = b ? lg[u][1] + p1 : lg[u][0] + p0;
      a1 = b ? lg[u][3] + p3 : lg[u][2] + p2;
      a2 = b ? lg[u][5] + p5 : lg[u][4] + p4;
      a3 = b ? lg[u][7] + p7 : lg[u][6] + p6;
    }
    double c0, c1;
    {
      double q0 = __shfl_xor(a0, 2, 64), q1 = __shfl_xor(a1, 2, 64);
      double q2 = __shfl_xor(a2, 2, 64), q3 = __shfl_xor(a3, 2, 64);
      bool b = (lane >> 1) & 1;
      c0 = b ? a1 + q1 : a0 + q0;
      c1 = b ? a3 + q3 : a2 + q2;
    }
    double c;
    {
      double r0 = __shfl_xor(c0, 4, 64), r1 = __shfl_xor(c1, 4, 64);
      bool b = (lane >> 2) & 1;
      c = b ? c1 + r1 : c0 + r0;
    }
    lred[u][wave][lane] = c;

    float sv = s[u], ssv = ss[u];
#pragma unroll
    for (int m = 1; m < 64; m <<= 1) {
      sv  += __shfl_xor(sv, m, 64);
      ssv += __shfl_xor(ssv, m, 64);
    }
    if (lane == 0) { wst[u][wave][0] = sv; wst[u][wave][1] = ssv; }
  }
  __syncthreads();

  // phase 2: wave u finishes token u's expert totals (parallel across waves)
  if (wave < TPB_TOK) {
    int u = wave;
    double t = lred[u][0][lane] + lred[u][1][lane]
             + lred[u][2][lane] + lred[u][3][lane];
    t += __shfl_xor(t, 8, 64);
    t += __shfl_xor(t, 16, 64);
    t += __shfl_xor(t, 32, 64);
    if (lane < E_NUM) etot[u][lane] = t;
    if (lane == 0) {
      stot[u][0] = wst[u][0][0] + wst[u][1][0] + wst[u][2][0] + wst[u][3][0];
      stot[u][1] = wst[u][0][1] + wst[u][1][1] + wst[u][2][1] + wst[u][3][1];
    }
  }
  __syncthreads();

  // phase 3: every thread reads the 8 totals (LDS broadcast) and finishes locally
#pragma unroll
  for (int u = 0; u < TPB_TOK; u++) {
    double bestv = etot[u][0]; int best = 0;
#pragma unroll
    for (int e = 1; e < E_NUM; e++) {
      double t = etot[u][e];
      if (t > bestv) { bestv = t; best = e; }   // first-max tiebreak
    }
    float mean = stot[u][0] * (1.0f / (float)D_DIM);
    float var  = stot[u][1] * (1.0f / (float)D_DIM) - mean * mean;
    float rstd = 1.0f / sqrtf(var + LN_EPS);
    if (tid == 0) eid[t0 + u] = best;
    float4 sc = ((const float4*)(ln_s + (size_t)best * D_DIM))[tid];
    float4 bi = ((const float4*)(ln_b + (size_t)best * D_DIM))[tid];
    ushort4 o;
    o.x = f2bf((v[u].x - mean) * rstd * sc.x + bi.x);
    o.y = f2bf((v[u].y - mean) * rstd * sc.y + bi.y);
    o.z = f2bf((v[u].z - mean) * rstd * sc.z + bi.z);
    o.w = f2bf((v[u].w - mean) * rstd * sc.w + bi.w);
    ((ushort4*)(xhat + (size_t)(t0 + u) * D_DIM))[tid] = o;
  }
}

// ---------------- route: histogram + scan + permutation, ZERO global atomics ----
__global__ __launch_bounds__(1024) void smoe_route(
    const int* __restrict__ eid, int* __restrict__ texp, int* __restrict__ tokp)
{
  int tid = threadIdx.x;
  int lane = tid & 63, wave = tid >> 6;   // 16 waves

  int cnt[E_NUM] = {};
  int ee[16];
#pragma unroll
  for (int j = 0; j < 16; j++) {
    int e = eid[j * 1024 + tid];
    ee[j] = e;
#pragma unroll
    for (int k = 0; k < E_NUM; k++) cnt[k] += (e == k);
  }
  int inc[E_NUM];
#pragma unroll
  for (int k = 0; k < E_NUM; k++) inc[k] = cnt[k];
#pragma unroll
  for (int m = 1; m < 64; m <<= 1) {
#pragma unroll
    for (int k = 0; k < E_NUM; k++) {
      int o = __shfl_up(inc[k], m, 64);
      if (lane >= m) inc[k] += o;
    }
  }
  __shared__ int wtot[16][E_NUM];
  __shared__ int wbase[16][E_NUM];
  __shared__ int ebase[E_NUM];
  __shared__ int ecnt[E_NUM];
  __shared__ int epad[E_NUM];
  if (lane == 63)
#pragma unroll
    for (int k = 0; k < E_NUM; k++) wtot[wave][k] = inc[k];
  __syncthreads();
  if (tid == 0) {
    int run[E_NUM] = {};
    for (int w = 0; w < 16; w++)
#pragma unroll
      for (int k = 0; k < E_NUM; k++) { wbase[w][k] = run[k]; run[k] += wtot[w][k]; }
    int b = 0, ti = 0;
    for (int k = 0; k < E_NUM; k++) {
      ecnt[k] = run[k];
      ebase[k] = b;
      int nt = (run[k] + BM - 1) / BM;
      for (int j = 0; j < nt; j++) texp[ti++] = k;
      epad[k] = nt * BM;
      b += nt * BM;
    }
    for (; ti < MAXTILES; ti++) texp[ti] = -1;
  }
  __syncthreads();
  int tb[E_NUM];
#pragma unroll
  for (int k = 0; k < E_NUM; k++) tb[k] = wbase[wave][k] + inc[k] - cnt[k];
  int run2[E_NUM] = {};
#pragma unroll
  for (int j = 0; j < 16; j++) {
    int e = ee[j];
    int r = 0;
#pragma unroll
    for (int k = 0; k < E_NUM; k++) {
      if (e == k) r = tb[k] + run2[k];
      run2[k] += (e == k);
    }
    tokp[ebase[e] + r] = j * 1024 + tid;
  }
#pragma unroll
  for (int k = 0; k < E_NUM; k++) {
    int s0 = ebase[k] + ecnt[k], n = epad[k] - ecnt[k];
    for (int i = tid; i < n; i += 1024) tokp[s0 + i] = -1;
  }
}

// ---------------- transpose-convert fp32 [E][R][C] -> bf16 [E][C][R] ----------------
__global__ __launch_bounds__(256) void smoe_cvt(
    const float* __restrict__ in, unsigned short* __restrict__ out, int R, int C)
{
  int rt = R / 32, ct = C / 32;
  int bid = blockIdx.x;
  int e = bid / (rt * ct);
  int rem = bid % (rt * ct);
  int r0 = (rem / ct) * 32, c0 = (rem % ct) * 32;
  __shared__ float tile[32][33];
  int tx = threadIdx.x & 31, ty = threadIdx.x >> 5;   // ty 0..7
  const float* src = in + (size_t)e * R * C;
#pragma unroll
  for (int i = 0; i < 4; i++)
    tile[ty + 8 * i][tx] = src[(size_t)(r0 + ty + 8 * i) * C + c0 + tx];
  __syncthreads();
  unsigned short* dst = out + (size_t)e * R * C;
#pragma unroll
  for (int i = 0; i < 4; i++)
    dst[(size_t)(c0 + ty + 8 * i) * R + r0 + tx] = f2bf(tile[tx][ty + 8 * i]);
}

// ---------------- GEMM1: h = gelu(xhat_gathered @ W1t^T + b1), bf16 out ----------------
// BN1=64 -> 544 blocks (load balance) + 12KB LDS (many blocks/CU for latency hiding)
__global__ __launch_bounds__(256) void smoe_gemm1(
    const unsigned short* __restrict__ xhat,   // [N][D]
    const unsigned short* __restrict__ w1t,    // [E][H][D]
    const float* __restrict__ b1,              // [E][H]
    const int* __restrict__ texp,
    const int* __restrict__ tokp,
    unsigned short* __restrict__ hbuf)         // [MP][H]
{
  int mt = blockIdx.x;
  int e = texp[mt];
  if (e < 0) return;
  int nt = blockIdx.y;                 // 0..3 over H
  int tid = threadIdx.x;
  __shared__ unsigned short As[BM * BK];
  __shared__ unsigned short Bs[BN1 * BK];
  int r = tid >> 2;                    // 0..63
  int c = tid & 3;                     // 16B chunk
  int row0 = mt * BM + r, row1 = row0 + 64;
  int tok0 = tokp[row0]; tok0 = tok0 < 0 ? 0 : tok0;
  int tok1 = tokp[row1]; tok1 = tok1 < 0 ? 0 : tok1;
  const unsigned short* a0 = xhat + (size_t)tok0 * D_DIM + c * 8;
  const unsigned short* a1 = xhat + (size_t)tok1 * D_DIM + c * 8;
  const unsigned short* bb = w1t + (size_t)e * H_DIM * D_DIM
                           + (size_t)(nt * BN1 + r) * D_DIM + c * 8;
  unsigned short* As0 = As + r * BK + c * 8;
  unsigned short* As1 = As + (r + 64) * BK + c * 8;
  unsigned short* Bs0 = Bs + r * BK + c * 8;

  int wave = tid >> 6, lane = tid & 63;
  int wr = (wave >> 1) * 64;
  int wc = (wave & 1) * 32;
  int qm = lane & 15;
  int quad = lane >> 4;
  f32x4 acc[4][2] = {};

  for (int k0 = 0; k0 < D_DIM; k0 += BK) {
    gl_lds16(a0 + k0, As0);
    gl_lds16(a1 + k0, As1);
    gl_lds16(bb + k0, Bs0);
    __syncthreads();
    bf16x8 af[4], bf[2];
#pragma unroll
    for (int i = 0; i < 4; i++)
      af[i] = *(const bf16x8*)(As + (wr + i * 16 + qm) * BK + quad * 8);
#pragma unroll
    for (int i = 0; i < 2; i++)
      bf[i] = *(const bf16x8*)(Bs + (wc + i * 16 + qm) * BK + quad * 8);
#pragma unroll
    for (int mi = 0; mi < 4; mi++)
#pragma unroll
      for (int ni = 0; ni < 2; ni++)
        acc[mi][ni] = __builtin_amdgcn_mfma_f32_16x16x32_bf16(
            af[mi], bf[ni], acc[mi][ni], 0, 0, 0);
    __syncthreads();
  }
  int mbase = mt * BM;
#pragma unroll
  for (int ni = 0; ni < 2; ni++) {
    int col = nt * BN1 + wc + ni * 16 + qm;
    float bias = b1[e * H_DIM + col];
#pragma unroll
    for (int mi = 0; mi < 4; mi++) {
      int rl = wr + mi * 16 + quad * 4;
#pragma unroll
      for (int i = 0; i < 4; i++) {
        float vv = acc[mi][ni][i] + bias;
        float g = 0.5f * vv * (1.0f + erff(vv * 0.70710678118654752f));
        hbuf[(size_t)(mbase + rl + i) * H_DIM + col] = f2bf(g);
      }
    }
  }
}

// ---------------- GEMM2: y[tok] = h @ W2t^T + b2, fp32 scatter ----------------
__global__ __launch_bounds__(256) void smoe_gemm2(
    const unsigned short* __restrict__ hbuf,   // [MP][H]
    const unsigned short* __restrict__ w2t,    // [E][D][H]
    const float* __restrict__ b2,              // [E][D]
    const int* __restrict__ texp,
    const int* __restrict__ tokp,
    float* __restrict__ y)                     // [N][D]
{
  int mt = blockIdx.x;
  int e = texp[mt];
  if (e < 0) return;
  int nt = blockIdx.y;                 // 0..7 over D
  int tid = threadIdx.x;
  __shared__ unsigned short As[BM * BK];
  __shared__ unsigned short Bs[BN * BK];
  int r = tid >> 2;
  int c = tid & 3;
  const unsigned short* a0 = hbuf + (size_t)(mt * BM + r) * H_DIM + c * 8;
  const unsigned short* a1 = a0 + (size_t)64 * H_DIM;
  const unsigned short* bb = w2t + (size_t)e * D_DIM * H_DIM
                           + (size_t)(nt * BN + r) * H_DIM + c * 8;
  const unsigned short* bb1 = bb + (size_t)64 * H_DIM;
  unsigned short* As0 = As + r * BK + c * 8;
  unsigned short* As1 = As + (r + 64) * BK + c * 8;
  unsigned short* Bs0 = Bs + r * BK + c * 8;
  unsigned short* Bs1 = Bs + (r + 64) * BK + c * 8;

  int wave = tid >> 6, lane = tid & 63;
  int wr = (wave >> 1) * 64;
  int wc = (wave & 1) * 64;
  int qm = lane & 15;
  int quad = lane >> 4;
  f32x4 acc[4][4] = {};

  for (int k0 = 0; k0 < H_DIM; k0 += BK) {   // 8 steps
    gl_lds16(a0 + k0, As0);
    gl_lds16(a1 + k0, As1);
    gl_lds16(bb + k0, Bs0);
    gl_lds16(bb1 + k0, Bs1);
    __syncthreads();
    bf16x8 af[4], bf[4];
#pragma unroll
    for (int i = 0; i < 4; i++) {
      af[i] = *(const bf16x8*)(As + (wr + i * 16 + qm) * BK + quad * 8);
      bf[i] = *(const bf16x8*)(Bs + (wc + i * 16 + qm) * BK + quad * 8);
    }
#pragma unroll
    for (int mi = 0; mi < 4; mi++)
#pragma unroll
      for (int ni = 0; ni < 4; ni++)
        acc[mi][ni] = __builtin_amdgcn_mfma_f32_16x16x32_bf16(
            af[mi], bf[ni], acc[mi][ni], 0, 0, 0);
    __syncthreads();
  }
  int mbase = mt * BM;
#pragma unroll
  for (int mi = 0; mi < 4; mi++) {
#pragma unroll
    for (int i = 0; i < 4; i++) {
      int row = mbase + wr + mi * 16 + quad * 4 + i;
      int tok = tokp[row];
      if (tok < 0) continue;
#pragma unroll
      for (int ni = 0; ni < 4; ni++) {
        int col = nt * BN + wc + ni * 16 + qm;
        y[(size_t)tok * D_DIM + col] = acc[mi][ni][i] + b2[e * D_DIM + col];
      }
    }
  }
}

extern "C" void kernel_launch(void* const* d_in, const int* in_sizes, int n_in,
                              void* d_out, int out_size, void* d_ws, size_t ws_size,
                              hipStream_t stream) {
  (void)in_sizes; (void)n_in; (void)out_size; (void)ws_size;
  const float* x    = (const float*)d_in[0];
  const float* wg   = (const float*)d_in[1];
  const float* ln_s = (const float*)d_in[2];
  const float* ln_b = (const float*)d_in[3];
  const float* w1   = (const float*)d_in[4];
  const float* b1   = (const float*)d_in[5];
  const float* w2   = (const float*)d_in[6];
  const float* b2   = (const float*)d_in[7];
  float* y = (float*)d_out;

  char* ws = (char*)d_ws;
  size_t off = 0;
  auto alloc = [&](size_t bytes) {
    void* p = ws + off;
    off = (off + bytes + 255) & ~(size_t)255;
    return p;
  };
  unsigned short* xhat = (unsigned short*)alloc((size_t)N_TOK * D_DIM * 2);          // 32 MB
  unsigned short* w1t  = (unsigned short*)alloc((size_t)E_NUM * D_DIM * H_DIM * 2);  // 4 MB
  unsigned short* w2t  = (unsigned short*)alloc((size_t)E_NUM * D_DIM * H_DIM * 2);  // 4 MB
  unsigned short* hbuf = (unsigned short*)alloc((size_t)MP * H_DIM * 2);             // 8.5 MB
  int* eid    = (int*)alloc((size_t)N_TOK * 4);
  int* tokp   = (int*)alloc((size_t)MP * 4);
  int* texp   = (int*)alloc((size_t)MAXTILES * 4);

  smoe_gate<<<N_TOK / TPB_TOK, 256, 0, stream>>>(x, wg, ln_s, ln_b, xhat, eid);
  smoe_route<<<1, 1024, 0, stream>>>(eid, texp, tokp);
  smoe_cvt<<<E_NUM * (D_DIM / 32) * (H_DIM / 32), 256, 0, stream>>>(w1, w1t, D_DIM, H_DIM);
  smoe_cvt<<<E_NUM * (H_DIM / 32) * (D_DIM / 32), 256, 0, stream>>>(w2, w2t, H_DIM, D_DIM);
  smoe_gemm1<<<dim3(MAXTILES, H_DIM / BN1), 256, 0, stream>>>(xhat, w1t, b1, texp, tokp, hbuf);
  smoe_gemm2<<<dim3(MAXTILES, D_DIM / BN), 256, 0, stream>>>(hbuf, w2t, b2, texp, tokp, y);
}

// Round 5
// 252.900 us; speedup vs baseline: 1.7611x; 1.0217x over previous
//
#include <hip/hip_runtime.h>
#include <hip/hip_bf16.h>
#include <math.h>

#define N_TOK 16384
#define D_DIM 1024
#define E_NUM 8
#define H_DIM 256
#define LN_EPS 1e-5f

#define BM 128
#define BN 128
#define BN1 64
#define BK 32
#define MAXTILES (N_TOK / BM + E_NUM)   /* 136 */
#define MP (MAXTILES * BM)              /* 17408 */

typedef __attribute__((ext_vector_type(8))) short bf16x8;
typedef __attribute__((ext_vector_type(4))) float f32x4;

__device__ __forceinline__ unsigned short f2bf(float f) {
  union { float f; unsigned u; } cv; cv.f = f;
  unsigned u = cv.u;
  u += 0x7fffu + ((u >> 16) & 1u);   // round-to-nearest-even
  return (unsigned short)(u >> 16);
}

__device__ __forceinline__ void gl_lds16(const void* g, void* l) {
  __builtin_amdgcn_global_load_lds(
      (const __attribute__((address_space(1))) unsigned int*)g,
      (__attribute__((address_space(3))) unsigned int*)l, 16, 0, 0);
}

// ---------------- gate + layernorm: ONE WAVE PER TOKEN ----------------
// DS-op count per token drops 160 -> ~55 (the round-4 LDS-pipe bottleneck).
// Lane owns dims {lane*4+256j}: same coalesced float4 map for x/wg/ln/xhat,
// valid because all reductions are over the full D.
__global__ __launch_bounds__(256) void smoe_gate(
    const float* __restrict__ x, const float* __restrict__ wg,
    const float* __restrict__ ln_s, const float* __restrict__ ln_b,
    unsigned short* __restrict__ xhat, int* __restrict__ eid)
{
  int lane = threadIdx.x & 63, wave = threadIdx.x >> 6;
  int t = blockIdx.x * 4 + wave;

  const float4* x4 = (const float4*)x + (size_t)t * 256;
  float4 v[4];
  float s = 0.f, ss = 0.f;
#pragma unroll
  for (int j = 0; j < 4; j++) {
    v[j] = x4[lane + 64 * j];
    s  += v[j].x + v[j].y + v[j].z + v[j].w;
    ss += v[j].x * v[j].x + v[j].y * v[j].y + v[j].z * v[j].z + v[j].w * v[j].w;
  }
  const float4* wg4 = (const float4*)wg;
  double lg[E_NUM];
#pragma unroll
  for (int e = 0; e < E_NUM; e++) {
    double acc = 0.0;
#pragma unroll
    for (int j = 0; j < 4; j++) {
      float4 w = wg4[e * 256 + lane + 64 * j];
      acc += (double)v[j].x * w.x + (double)v[j].y * w.y
           + (double)v[j].z * w.z + (double)v[j].w * w.w;
    }
    lg[e] = acc;
  }

  // reduce-scatter 8 -> 1 per lane (expert = lane&7)
  double a0, a1, a2, a3;
  {
    double p0 = __shfl_xor(lg[0], 1, 64), p1 = __shfl_xor(lg[1], 1, 64);
    double p2 = __shfl_xor(lg[2], 1, 64), p3 = __shfl_xor(lg[3], 1, 64);
    double p4 = __shfl_xor(lg[4], 1, 64), p5 = __shfl_xor(lg[5], 1, 64);
    double p6 = __shfl_xor(lg[6], 1, 64), p7 = __shfl_xor(lg[7], 1, 64);
    bool b = lane & 1;
    a0 = b ? lg[1] + p1 : lg[0] + p0;
    a1 = b ? lg[3] + p3 : lg[2] + p2;
    a2 = b ? lg[5] + p5 : lg[4] + p4;
    a3 = b ? lg[7] + p7 : lg[6] + p6;
  }
  double c0, c1;
  {
    double q0 = __shfl_xor(a0, 2, 64), q1 = __shfl_xor(a1, 2, 64);
    double q2 = __shfl_xor(a2, 2, 64), q3 = __shfl_xor(a3, 2, 64);
    bool b = (lane >> 1) & 1;
    c0 = b ? a1 + q1 : a0 + q0;
    c1 = b ? a3 + q3 : a2 + q2;
  }
  double c;
  {
    double r0 = __shfl_xor(c0, 4, 64), r1 = __shfl_xor(c1, 4, 64);
    bool b = (lane >> 2) & 1;
    c = b ? c1 + r1 : c0 + r0;
  }
  c += __shfl_xor(c, 8, 64);
  c += __shfl_xor(c, 16, 64);
  c += __shfl_xor(c, 32, 64);   // every lane: total logit for expert lane&7

  // argmax butterfly within the 8-lane group (first-max tiebreak)
  double val = c; int idx = lane & 7;
#pragma unroll
  for (int m = 1; m < E_NUM; m <<= 1) {
    double ov = __shfl_xor(val, m, 64);
    int    oi = __shfl_xor(idx, m, 64);
    if (ov > val || (ov == val && oi < idx)) { val = ov; idx = oi; }
  }
  int best = idx;

  // stats butterfly
#pragma unroll
  for (int m = 1; m < 64; m <<= 1) {
    s  += __shfl_xor(s, m, 64);
    ss += __shfl_xor(ss, m, 64);
  }
  float mean = s * (1.0f / (float)D_DIM);
  float var  = ss * (1.0f / (float)D_DIM) - mean * mean;
  float rstd = 1.0f / sqrtf(var + LN_EPS);

  if (lane == 0) eid[t] = best;

  const float4* s4 = (const float4*)(ln_s + (size_t)best * D_DIM);
  const float4* b4 = (const float4*)(ln_b + (size_t)best * D_DIM);
  ushort4* xo = (ushort4*)(xhat + (size_t)t * D_DIM);
#pragma unroll
  for (int j = 0; j < 4; j++) {
    float4 sc = s4[lane + 64 * j], bi = b4[lane + 64 * j];
    ushort4 o;
    o.x = f2bf((v[j].x - mean) * rstd * sc.x + bi.x);
    o.y = f2bf((v[j].y - mean) * rstd * sc.y + bi.y);
    o.z = f2bf((v[j].z - mean) * rstd * sc.z + bi.z);
    o.w = f2bf((v[j].w - mean) * rstd * sc.w + bi.w);
    xo[lane + 64 * j] = o;
  }
}

// ---------------- route: histogram + scan + permutation, ZERO global atomics ----
__global__ __launch_bounds__(1024) void smoe_route(
    const int* __restrict__ eid, int* __restrict__ texp, int* __restrict__ tokp)
{
  int tid = threadIdx.x;
  int lane = tid & 63, wave = tid >> 6;   // 16 waves

  int cnt[E_NUM] = {};
  int ee[16];
#pragma unroll
  for (int j = 0; j < 16; j++) {
    int e = eid[j * 1024 + tid];
    ee[j] = e;
#pragma unroll
    for (int k = 0; k < E_NUM; k++) cnt[k] += (e == k);
  }
  int inc[E_NUM];
#pragma unroll
  for (int k = 0; k < E_NUM; k++) inc[k] = cnt[k];
#pragma unroll
  for (int m = 1; m < 64; m <<= 1) {
#pragma unroll
    for (int k = 0; k < E_NUM; k++) {
      int o = __shfl_up(inc[k], m, 64);
      if (lane >= m) inc[k] += o;
    }
  }
  __shared__ int wtot[16][E_NUM];
  __shared__ int wbase[16][E_NUM];
  __shared__ int ebase[E_NUM];
  __shared__ int ecnt[E_NUM];
  __shared__ int epad[E_NUM];
  if (lane == 63)
#pragma unroll
    for (int k = 0; k < E_NUM; k++) wtot[wave][k] = inc[k];
  __syncthreads();
  if (tid == 0) {
    int run[E_NUM] = {};
    for (int w = 0; w < 16; w++)
#pragma unroll
      for (int k = 0; k < E_NUM; k++) { wbase[w][k] = run[k]; run[k] += wtot[w][k]; }
    int b = 0, ti = 0;
    for (int k = 0; k < E_NUM; k++) {
      ecnt[k] = run[k];
      ebase[k] = b;
      int nt = (run[k] + BM - 1) / BM;
      for (int j = 0; j < nt; j++) texp[ti++] = k;
      epad[k] = nt * BM;
      b += nt * BM;
    }
    for (; ti < MAXTILES; ti++) texp[ti] = -1;
  }
  __syncthreads();
  int tb[E_NUM];
#pragma unroll
  for (int k = 0; k < E_NUM; k++) tb[k] = wbase[wave][k] + inc[k] - cnt[k];
  int run2[E_NUM] = {};
#pragma unroll
  for (int j = 0; j < 16; j++) {
    int e = ee[j];
    int r = 0;
#pragma unroll
    for (int k = 0; k < E_NUM; k++) {
      if (e == k) r = tb[k] + run2[k];
      run2[k] += (e == k);
    }
    tokp[ebase[e] + r] = j * 1024 + tid;
  }
#pragma unroll
  for (int k = 0; k < E_NUM; k++) {
    int s0 = ebase[k] + ecnt[k], n = epad[k] - ecnt[k];
    for (int i = tid; i < n; i += 1024) tokp[s0 + i] = -1;
  }
}

// ---------------- transpose-convert BOTH weights in one launch ----------------
// fp32 [E][R][C] -> bf16 [E][C][R]; blocks 0..2047 = W1 (R=1024,C=256),
// blocks 2048..4095 = W2 (R=256,C=1024).
__global__ __launch_bounds__(256) void smoe_cvt2(
    const float* __restrict__ w1, unsigned short* __restrict__ w1t,
    const float* __restrict__ w2, unsigned short* __restrict__ w2t)
{
  int bid = blockIdx.x;
  const float* in; unsigned short* out; int R, C;
  if (bid < 2048) { in = w1; out = w1t; R = D_DIM; C = H_DIM; }
  else            { in = w2; out = w2t; R = H_DIM; C = D_DIM; bid -= 2048; }
  int rt = R / 32, ct = C / 32;
  int e = bid / (rt * ct);
  int rem = bid % (rt * ct);
  int r0 = (rem / ct) * 32, c0 = (rem % ct) * 32;
  __shared__ float tile[32][33];
  int tx = threadIdx.x & 31, ty = threadIdx.x >> 5;   // ty 0..7
  const float* src = in + (size_t)e * R * C;
#pragma unroll
  for (int i = 0; i < 4; i++)
    tile[ty + 8 * i][tx] = src[(size_t)(r0 + ty + 8 * i) * C + c0 + tx];
  __syncthreads();
  unsigned short* dst = out + (size_t)e * R * C;
#pragma unroll
  for (int i = 0; i < 4; i++)
    dst[(size_t)(c0 + ty + 8 * i) * R + r0 + tx] = f2bf(tile[tx][ty + 8 * i]);
}

// ---------------- GEMM1: h = gelu(xhat_gathered @ W1t^T + b1), bf16 out ----------------
__global__ __launch_bounds__(256) void smoe_gemm1(
    const unsigned short* __restrict__ xhat,   // [N][D]
    const unsigned short* __restrict__ w1t,    // [E][H][D]
    const float* __restrict__ b1,              // [E][H]
    const int* __restrict__ texp,
    const int* __restrict__ tokp,
    unsigned short* __restrict__ hbuf)         // [MP][H]
{
  int mt = blockIdx.x;
  int e = texp[mt];
  if (e < 0) return;
  int nt = blockIdx.y;                 // 0..3 over H
  int tid = threadIdx.x;
  __shared__ unsigned short As[BM * BK];
  __shared__ unsigned short Bs[BN1 * BK];
  int r = tid >> 2;                    // 0..63
  int c = tid & 3;                     // 16B chunk
  int row0 = mt * BM + r, row1 = row0 + 64;
  int tok0 = tokp[row0]; tok0 = tok0 < 0 ? 0 : tok0;
  int tok1 = tokp[row1]; tok1 = tok1 < 0 ? 0 : tok1;
  const unsigned short* a0 = xhat + (size_t)tok0 * D_DIM + c * 8;
  const unsigned short* a1 = xhat + (size_t)tok1 * D_DIM + c * 8;
  const unsigned short* bb = w1t + (size_t)e * H_DIM * D_DIM
                           + (size_t)(nt * BN1 + r) * D_DIM + c * 8;
  unsigned short* As0 = As + r * BK + c * 8;
  unsigned short* As1 = As + (r + 64) * BK + c * 8;
  unsigned short* Bs0 = Bs + r * BK + c * 8;

  int wave = tid >> 6, lane = tid & 63;
  int wr = (wave >> 1) * 64;
  int wc = (wave & 1) * 32;
  int qm = lane & 15;
  int quad = lane >> 4;
  f32x4 acc[4][2] = {};

  for (int k0 = 0; k0 < D_DIM; k0 += BK) {
    gl_lds16(a0 + k0, As0);
    gl_lds16(a1 + k0, As1);
    gl_lds16(bb + k0, Bs0);
    __syncthreads();
    bf16x8 af[4], bf[2];
#pragma unroll
    for (int i = 0; i < 4; i++)
      af[i] = *(const bf16x8*)(As + (wr + i * 16 + qm) * BK + quad * 8);
#pragma unroll
    for (int i = 0; i < 2; i++)
      bf[i] = *(const bf16x8*)(Bs + (wc + i * 16 + qm) * BK + quad * 8);
#pragma unroll
    for (int mi = 0; mi < 4; mi++)
#pragma unroll
      for (int ni = 0; ni < 2; ni++)
        acc[mi][ni] = __builtin_amdgcn_mfma_f32_16x16x32_bf16(
            af[mi], bf[ni], acc[mi][ni], 0, 0, 0);
    __syncthreads();
  }
  int mbase = mt * BM;
#pragma unroll
  for (int ni = 0; ni < 2; ni++) {
    int col = nt * BN1 + wc + ni * 16 + qm;
    float bias = b1[e * H_DIM + col];
#pragma unroll
    for (int mi = 0; mi < 4; mi++) {
      int rl = wr + mi * 16 + quad * 4;
#pragma unroll
      for (int i = 0; i < 4; i++) {
        float vv = acc[mi][ni][i] + bias;
        float g = 0.5f * vv * (1.0f + erff(vv * 0.70710678118654752f));
        hbuf[(size_t)(mbase + rl + i) * H_DIM + col] = f2bf(g);
      }
    }
  }
}

// ---------------- GEMM2: y[tok] = h @ W2t^T + b2, fp32 scatter ----------------
__global__ __launch_bounds__(256) void smoe_gemm2(
    const unsigned short* __restrict__ hbuf,   // [MP][H]
    const unsigned short* __restrict__ w2t,    // [E][D][H]
    const float* __restrict__ b2,              // [E][D]
    const int* __restrict__ texp,
    const int* __restrict__ tokp,
    float* __restrict__ y)                     // [N][D]
{
  int mt = blockIdx.x;
  int e = texp[mt];
  if (e < 0) return;
  int nt = blockIdx.y;                 // 0..7 over D
  int tid = threadIdx.x;
  __shared__ unsigned short As[BM * BK];
  __shared__ unsigned short Bs[BN * BK];
  int r = tid >> 2;
  int c = tid & 3;
  const unsigned short* a0 = hbuf + (size_t)(mt * BM + r) * H_DIM + c * 8;
  const unsigned short* a1 = a0 + (size_t)64 * H_DIM;
  const unsigned short* bb = w2t + (size_t)e * D_DIM * H_DIM
                           + (size_t)(nt * BN + r) * H_DIM + c * 8;
  const unsigned short* bb1 = bb + (size_t)64 * H_DIM;
  unsigned short* As0 = As + r * BK + c * 8;
  unsigned short* As1 = As + (r + 64) * BK + c * 8;
  unsigned short* Bs0 = Bs + r * BK + c * 8;
  unsigned short* Bs1 = Bs + (r + 64) * BK + c * 8;

  int wave = tid >> 6, lane = tid & 63;
  int wr = (wave >> 1) * 64;
  int wc = (wave & 1) * 64;
  int qm = lane & 15;
  int quad = lane >> 4;
  f32x4 acc[4][4] = {};

  for (int k0 = 0; k0 < H_DIM; k0 += BK) {   // 8 steps
    gl_lds16(a0 + k0, As0);
    gl_lds16(a1 + k0, As1);
    gl_lds16(bb + k0, Bs0);
    gl_lds16(bb1 + k0, Bs1);
    __syncthreads();
    bf16x8 af[4], bf[4];
#pragma unroll
    for (int i = 0; i < 4; i++) {
      af[i] = *(const bf16x8*)(As + (wr + i * 16 + qm) * BK + quad * 8);
      bf[i] = *(const bf16x8*)(Bs + (wc + i * 16 + qm) * BK + quad * 8);
    }
#pragma unroll
    for (int mi = 0; mi < 4; mi++)
#pragma unroll
      for (int ni = 0; ni < 4; ni++)
        acc[mi][ni] = __builtin_amdgcn_mfma_f32_16x16x32_bf16(
            af[mi], bf[ni], acc[mi][ni], 0, 0, 0);
    __syncthreads();
  }
  int mbase = mt * BM;
#pragma unroll
  for (int mi = 0; mi < 4; mi++) {
#pragma unroll
    for (int i = 0; i < 4; i++) {
      int row = mbase + wr + mi * 16 + quad * 4 + i;
      int tok = tokp[row];
      if (tok < 0) continue;
#pragma unroll
      for (int ni = 0; ni < 4; ni++) {
        int col = nt * BN + wc + ni * 16 + qm;
        y[(size_t)tok * D_DIM + col] = acc[mi][ni][i] + b2[e * D_DIM + col];
      }
    }
  }
}

extern "C" void kernel_launch(void* const* d_in, const int* in_sizes, int n_in,
                              void* d_out, int out_size, void* d_ws, size_t ws_size,
                              hipStream_t stream) {
  (void)in_sizes; (void)n_in; (void)out_size; (void)ws_size;
  const float* x    = (const float*)d_in[0];
  const float* wg   = (const float*)d_in[1];
  const float* ln_s = (const float*)d_in[2];
  const float* ln_b = (const float*)d_in[3];
  const float* w1   = (const float*)d_in[4];
  const float* b1   = (const float*)d_in[5];
  const float* w2   = (const float*)d_in[6];
  const float* b2   = (const float*)d_in[7];
  float* y = (float*)d_out;

  char* ws = (char*)d_ws;
  size_t off = 0;
  auto alloc = [&](size_t bytes) {
    void* p = ws + off;
    off = (off + bytes + 255) & ~(size_t)255;
    return p;
  };
  unsigned short* xhat = (unsigned short*)alloc((size_t)N_TOK * D_DIM * 2);          // 32 MB
  unsigned short* w1t  = (unsigned short*)alloc((size_t)E_NUM * D_DIM * H_DIM * 2);  // 4 MB
  unsigned short* w2t  = (unsigned short*)alloc((size_t)E_NUM * D_DIM * H_DIM * 2);  // 4 MB
  unsigned short* hbuf = (unsigned short*)alloc((size_t)MP * H_DIM * 2);             // 8.5 MB
  int* eid    = (int*)alloc((size_t)N_TOK * 4);
  int* tokp   = (int*)alloc((size_t)MP * 4);
  int* texp   = (int*)alloc((size_t)MAXTILES * 4);

  smoe_gate<<<N_TOK / 4, 256, 0, stream>>>(x, wg, ln_s, ln_b, xhat, eid);
  smoe_route<<<1, 1024, 0, stream>>>(eid, texp, tokp);
  smoe_cvt2<<<4096, 256, 0, stream>>>(w1, w1t, w2, w2t);
  smoe_gemm1<<<dim3(MAXTILES, H_DIM / BN1), 256, 0, stream>>>(xhat, w1t, b1, texp, tokp, hbuf);
  smoe_gemm2<<<dim3(MAXTILES, D_DIM / BN), 256, 0, stream>>>(hbuf, w2t, b2, texp, tokp, y);
}